// Round 2
// baseline (243.185 us; speedup 1.0000x reference)
//
#include <hip/hip_runtime.h>
#include <math.h>

#define NUM_K 512
#define DIM   64
#define CHUNK 128
#define NCHUNK (NUM_K / CHUNK)
#define HW    4096
#define IMG   (DIM * HW)
#define OUT_Q 8388608
#define LOSS_OFF OUT_Q
#define IDX_OFF (OUT_Q + 1)
#define TPB   256
#define NBLK  512

__launch_bounds__(TPB, 2)
__global__ void vq_main(const float* __restrict__ in,
                        const float* __restrict__ emb,
                        float* __restrict__ out,
                        double* __restrict__ partial) {
  __shared__ float  es[CHUNK * DIM];   // 32 KB codebook chunk
  __shared__ float  se[CHUNK];         // ||e||^2 per code in chunk
  __shared__ double red[TPB / 64];

  const int tid = threadIdx.x;
  const int p   = blockIdx.x * TPB + tid;   // pixel id = n*4096 + h*64 + w
  const int n   = p >> 12;
  const int hw  = p & (HW - 1);
  const float* inp = in + n * IMG + hw;

  // load x row (NCHW: stride HW between features; coalesced across lanes)
  float x[DIM];
#pragma unroll
  for (int c = 0; c < DIM; ++c) x[c] = inp[c * HW];

  // ||x||^2, sequential fp32 chain (faithful to reference rounding scale)
  float sx = 0.f;
#pragma unroll
  for (int c = 0; c < DIM; ++c) sx = fmaf(x[c], x[c], sx);

  float best = INFINITY;
  int   bk   = 0;

  for (int ch = 0; ch < NCHUNK; ++ch) {
    // stage 128 codes -> LDS (coalesced float4)
    const float4* src = (const float4*)(emb + ch * CHUNK * DIM);
    float4* dst = (float4*)es;
#pragma unroll
    for (int i = 0; i < (CHUNK * DIM / 4) / TPB; ++i)
      dst[tid + i * TPB] = src[tid + i * TPB];
    __syncthreads();
    // ||e||^2 per code, sequential fp32
    if (tid < CHUNK) {
      float s = 0.f;
#pragma unroll
      for (int d = 0; d < DIM; ++d) s = fmaf(es[tid * DIM + d], es[tid * DIM + d], s);
      se[tid] = s;
    }
    __syncthreads();

    const float4* e4 = (const float4*)es;
    for (int k0 = 0; k0 < CHUNK; k0 += 4) {
      float a0 = 0.f, a1 = 0.f, a2 = 0.f, a3 = 0.f;
#pragma unroll
      for (int d4 = 0; d4 < DIM / 4; ++d4) {
        // broadcast reads: all lanes same address -> conflict-free
        const float4 e0 = e4[(k0 + 0) * (DIM / 4) + d4];
        const float4 e1 = e4[(k0 + 1) * (DIM / 4) + d4];
        const float4 e2 = e4[(k0 + 2) * (DIM / 4) + d4];
        const float4 e3 = e4[(k0 + 3) * (DIM / 4) + d4];
        const float x0 = x[4 * d4 + 0], x1 = x[4 * d4 + 1];
        const float x2 = x[4 * d4 + 2], x3 = x[4 * d4 + 3];
        // 4 independent chains, each d-ascending sequential (argmin-faithful)
        a0 = fmaf(x0, e0.x, a0); a1 = fmaf(x0, e1.x, a1);
        a2 = fmaf(x0, e2.x, a2); a3 = fmaf(x0, e3.x, a3);
        a0 = fmaf(x1, e0.y, a0); a1 = fmaf(x1, e1.y, a1);
        a2 = fmaf(x1, e2.y, a2); a3 = fmaf(x1, e3.y, a3);
        a0 = fmaf(x2, e0.z, a0); a1 = fmaf(x2, e1.z, a1);
        a2 = fmaf(x2, e2.z, a2); a3 = fmaf(x2, e3.z, a3);
        a0 = fmaf(x3, e0.w, a0); a1 = fmaf(x3, e1.w, a1);
        a2 = fmaf(x3, e2.w, a2); a3 = fmaf(x3, e3.w, a3);
      }
      const int kb = ch * CHUNK + k0;
      // d = (||x||^2 + ||e||^2) - 2*dot ; 2*a is exact in binary fp, so the
      // value matches the reference's two-step fp32 evaluation.
      const float d0 = (sx + se[k0 + 0]) - 2.f * a0;
      const float d1 = (sx + se[k0 + 1]) - 2.f * a1;
      const float d2 = (sx + se[k0 + 2]) - 2.f * a2;
      const float d3 = (sx + se[k0 + 3]) - 2.f * a3;
      // strict < with ascending k == np.argmin first-occurrence tie-break
      if (d0 < best) { best = d0; bk = kb + 0; }
      if (d1 < best) { best = d1; bk = kb + 1; }
      if (d2 < best) { best = d2; bk = kb + 2; }
      if (d3 < best) { best = d3; bk = kb + 3; }
    }
    __syncthreads();
  }

  // gather quantized row from global codebook (L1/L2-resident, 128 KB)
  const float* eb = emb + bk * DIM;
  float* outq = out + n * IMG + hw;
  float l = 0.f;
#pragma unroll
  for (int c = 0; c < DIM; ++c) {
    const float q = eb[c];
    outq[c * HW] = q;          // NCHW store, coalesced per c
    const float dd = q - x[c];
    l = fmaf(dd, dd, l);
  }
  out[IDX_OFF + p] = (float)bk;   // harness reads whole buffer as fp32

  // block-reduce commitment-loss partial into d_ws (double)
  double ls = (double)l;
#pragma unroll
  for (int o = 32; o; o >>= 1) ls += __shfl_down(ls, o);
  if ((tid & 63) == 0) red[tid >> 6] = ls;
  __syncthreads();
  if (tid == 0) {
    double t = 0.0;
#pragma unroll
    for (int w = 0; w < TPB / 64; ++w) t += red[w];
    partial[blockIdx.x] = t;
  }
}

__global__ void vq_loss(const double* __restrict__ partial, float* __restrict__ out) {
  __shared__ double r2[4];
  const int tid = threadIdx.x;
  double s = partial[tid] + partial[tid + 256];
#pragma unroll
  for (int o = 32; o; o >>= 1) s += __shfl_down(s, o);
  if ((tid & 63) == 0) r2[tid >> 6] = s;
  __syncthreads();
  if (tid == 0) {
    const double t = r2[0] + r2[1] + r2[2] + r2[3];
    out[LOSS_OFF] = (float)(0.25 * t / (double)OUT_Q);
  }
}

extern "C" void kernel_launch(void* const* d_in, const int* in_sizes, int n_in,
                              void* d_out, int out_size, void* d_ws, size_t ws_size,
                              hipStream_t stream) {
  (void)in_sizes; (void)n_in; (void)out_size; (void)ws_size;
  const float* in  = (const float*)d_in[0];
  const float* emb = (const float*)d_in[1];
  float* out = (float*)d_out;
  double* partial = (double*)d_ws;   // 512 doubles, fully overwritten each call
  vq_main<<<NBLK, TPB, 0, stream>>>(in, emb, out, partial);
  vq_loss<<<1, 256, 0, stream>>>(partial, out);
}

// Round 3
// 226.231 us; speedup vs baseline: 1.0749x; 1.0749x over previous
//
#include <hip/hip_runtime.h>
#include <math.h>

#define NUM_K 512
#define DIM   64
#define CHUNK 128
#define NCHUNK (NUM_K / CHUNK)
#define HW    4096
#define IMG   (DIM * HW)
#define OUT_Q 8388608
#define LOSS_OFF OUT_Q
#define IDX_OFF (OUT_Q + 1)
#define TPB   256
#define NBLK  512

typedef float f4 __attribute__((ext_vector_type(4)));

__launch_bounds__(TPB)
__global__ void vq_main(const float* __restrict__ in,
                        const float* __restrict__ emb,
                        float* __restrict__ out,
                        double* __restrict__ partial) {
  __shared__ f4     es[CHUNK * (DIM / 4)];  // 32 KB codebook chunk (f4-major)
  __shared__ float  se[NUM_K];              // ||e||^2 for ALL codes (2 KB)
  __shared__ double red[TPB / 64];

  const int tid = threadIdx.x;
  const int p   = blockIdx.x * TPB + tid;   // pixel id = n*4096 + h*64 + w
  const int n   = p >> 12;
  const int hw  = p & (HW - 1);
  const float* inp = in + n * IMG + hw;

  // x row in registers (NCHW: stride HW between features; coalesced across lanes)
  float xr[DIM];
#pragma unroll
  for (int c = 0; c < DIM; ++c) xr[c] = inp[c * HW];
  // Pin xr live in VGPRs: forbid rematerialization of the global loads into
  // the inner loop (round-2 showed VGPR=60 -> compiler reloaded x per use).
  asm volatile("" : "+v"(xr[ 0]),"+v"(xr[ 1]),"+v"(xr[ 2]),"+v"(xr[ 3]),
                    "+v"(xr[ 4]),"+v"(xr[ 5]),"+v"(xr[ 6]),"+v"(xr[ 7]),
                    "+v"(xr[ 8]),"+v"(xr[ 9]),"+v"(xr[10]),"+v"(xr[11]),
                    "+v"(xr[12]),"+v"(xr[13]),"+v"(xr[14]),"+v"(xr[15]));
  asm volatile("" : "+v"(xr[16]),"+v"(xr[17]),"+v"(xr[18]),"+v"(xr[19]),
                    "+v"(xr[20]),"+v"(xr[21]),"+v"(xr[22]),"+v"(xr[23]),
                    "+v"(xr[24]),"+v"(xr[25]),"+v"(xr[26]),"+v"(xr[27]),
                    "+v"(xr[28]),"+v"(xr[29]),"+v"(xr[30]),"+v"(xr[31]));
  asm volatile("" : "+v"(xr[32]),"+v"(xr[33]),"+v"(xr[34]),"+v"(xr[35]),
                    "+v"(xr[36]),"+v"(xr[37]),"+v"(xr[38]),"+v"(xr[39]),
                    "+v"(xr[40]),"+v"(xr[41]),"+v"(xr[42]),"+v"(xr[43]),
                    "+v"(xr[44]),"+v"(xr[45]),"+v"(xr[46]),"+v"(xr[47]));
  asm volatile("" : "+v"(xr[48]),"+v"(xr[49]),"+v"(xr[50]),"+v"(xr[51]),
                    "+v"(xr[52]),"+v"(xr[53]),"+v"(xr[54]),"+v"(xr[55]),
                    "+v"(xr[56]),"+v"(xr[57]),"+v"(xr[58]),"+v"(xr[59]),
                    "+v"(xr[60]),"+v"(xr[61]),"+v"(xr[62]),"+v"(xr[63]));

  // ||x||^2, sequential d-ascending fp32 chain (argmin-faithful)
  float sx = 0.f;
#pragma unroll
  for (int c = 0; c < DIM; ++c) sx = fmaf(xr[c], xr[c], sx);

  // ||e||^2 for all 512 codes, once per block, straight from global (L2-hot).
  // d-ascending sequential chain, no LDS row reads -> no bank conflicts.
  const f4* ef4 = (const f4*)emb;
#pragma unroll
  for (int r = 0; r < NUM_K / TPB; ++r) {
    const int k = tid + r * TPB;
    float s = 0.f;
#pragma unroll
    for (int j = 0; j < DIM / 4; ++j) {
      const f4 v = ef4[k * (DIM / 4) + j];
      s = fmaf(v.x, v.x, s); s = fmaf(v.y, v.y, s);
      s = fmaf(v.z, v.z, s); s = fmaf(v.w, v.w, s);
    }
    se[k] = s;
  }

  float best = INFINITY;
  int   bk   = 0;

  for (int ch = 0; ch < NCHUNK; ++ch) {
    // stage 128 codes -> LDS (coalesced 16B)
    const f4* src = ef4 + ch * CHUNK * (DIM / 4);
#pragma unroll
    for (int i = 0; i < (CHUNK * DIM / 4) / TPB; ++i)
      es[tid + i * TPB] = src[tid + i * TPB];
    __syncthreads();   // also covers se[] writes before first use

    for (int k0 = 0; k0 < CHUNK; k0 += 8) {
      float a0 = 0.f, a1 = 0.f, a2 = 0.f, a3 = 0.f;
      float a4 = 0.f, a5 = 0.f, a6 = 0.f, a7 = 0.f;
#pragma unroll
      for (int d4 = 0; d4 < DIM / 4; ++d4) {
        // wave-uniform broadcast reads: conflict-free
        const f4 e0 = es[(k0 + 0) * (DIM / 4) + d4];
        const f4 e1 = es[(k0 + 1) * (DIM / 4) + d4];
        const f4 e2 = es[(k0 + 2) * (DIM / 4) + d4];
        const f4 e3 = es[(k0 + 3) * (DIM / 4) + d4];
        const f4 e4v = es[(k0 + 4) * (DIM / 4) + d4];
        const f4 e5 = es[(k0 + 5) * (DIM / 4) + d4];
        const f4 e6 = es[(k0 + 6) * (DIM / 4) + d4];
        const f4 e7 = es[(k0 + 7) * (DIM / 4) + d4];
        const float x0 = xr[4 * d4 + 0], x1 = xr[4 * d4 + 1];
        const float x2 = xr[4 * d4 + 2], x3 = xr[4 * d4 + 3];
        // 8 independent chains, each d-ascending sequential (argmin-faithful)
        a0 = fmaf(x0, e0.x, a0); a1 = fmaf(x0, e1.x, a1);
        a2 = fmaf(x0, e2.x, a2); a3 = fmaf(x0, e3.x, a3);
        a4 = fmaf(x0, e4v.x, a4); a5 = fmaf(x0, e5.x, a5);
        a6 = fmaf(x0, e6.x, a6); a7 = fmaf(x0, e7.x, a7);
        a0 = fmaf(x1, e0.y, a0); a1 = fmaf(x1, e1.y, a1);
        a2 = fmaf(x1, e2.y, a2); a3 = fmaf(x1, e3.y, a3);
        a4 = fmaf(x1, e4v.y, a4); a5 = fmaf(x1, e5.y, a5);
        a6 = fmaf(x1, e6.y, a6); a7 = fmaf(x1, e7.y, a7);
        a0 = fmaf(x2, e0.z, a0); a1 = fmaf(x2, e1.z, a1);
        a2 = fmaf(x2, e2.z, a2); a3 = fmaf(x2, e3.z, a3);
        a4 = fmaf(x2, e4v.z, a4); a5 = fmaf(x2, e5.z, a5);
        a6 = fmaf(x2, e6.z, a6); a7 = fmaf(x2, e7.z, a7);
        a0 = fmaf(x3, e0.w, a0); a1 = fmaf(x3, e1.w, a1);
        a2 = fmaf(x3, e2.w, a2); a3 = fmaf(x3, e3.w, a3);
        a4 = fmaf(x3, e4v.w, a4); a5 = fmaf(x3, e5.w, a5);
        a6 = fmaf(x3, e6.w, a6); a7 = fmaf(x3, e7.w, a7);
      }
      const int kb = ch * CHUNK + k0;
      // d = (||x||^2 + ||e||^2) - 2*dot ; 2*a exact in binary fp.
      const float d0 = (sx + se[kb + 0]) - 2.f * a0;
      const float d1 = (sx + se[kb + 1]) - 2.f * a1;
      const float d2 = (sx + se[kb + 2]) - 2.f * a2;
      const float d3 = (sx + se[kb + 3]) - 2.f * a3;
      const float d4_ = (sx + se[kb + 4]) - 2.f * a4;
      const float d5 = (sx + se[kb + 5]) - 2.f * a5;
      const float d6 = (sx + se[kb + 6]) - 2.f * a6;
      const float d7 = (sx + se[kb + 7]) - 2.f * a7;
      // strict < with ascending k == np.argmin first-occurrence tie-break
      if (d0 < best) { best = d0; bk = kb + 0; }
      if (d1 < best) { best = d1; bk = kb + 1; }
      if (d2 < best) { best = d2; bk = kb + 2; }
      if (d3 < best) { best = d3; bk = kb + 3; }
      if (d4_ < best) { best = d4_; bk = kb + 4; }
      if (d5 < best) { best = d5; bk = kb + 5; }
      if (d6 < best) { best = d6; bk = kb + 6; }
      if (d7 < best) { best = d7; bk = kb + 7; }
    }
    __syncthreads();
  }

  // gather quantized row from global codebook (L2-resident, 128 KB)
  const float* eb = emb + bk * DIM;
  float* outq = out + n * IMG + hw;
  float l = 0.f;
#pragma unroll
  for (int c = 0; c < DIM; ++c) {
    const float q = eb[c];
    outq[c * HW] = q;          // NCHW store, coalesced per c
    const float dd = q - xr[c];
    l = fmaf(dd, dd, l);
  }
  out[IDX_OFF + p] = (float)bk;   // harness reads whole buffer as fp32

  // block-reduce commitment-loss partial into d_ws (double)
  double ls = (double)l;
#pragma unroll
  for (int o = 32; o; o >>= 1) ls += __shfl_down(ls, o);
  if ((tid & 63) == 0) red[tid >> 6] = ls;
  __syncthreads();
  if (tid == 0) {
    double t = 0.0;
#pragma unroll
    for (int w = 0; w < TPB / 64; ++w) t += red[w];
    partial[blockIdx.x] = t;
  }
}

__global__ void vq_loss(const double* __restrict__ partial, float* __restrict__ out) {
  __shared__ double r2[4];
  const int tid = threadIdx.x;
  double s = partial[tid] + partial[tid + 256];
#pragma unroll
  for (int o = 32; o; o >>= 1) s += __shfl_down(s, o);
  if ((tid & 63) == 0) r2[tid >> 6] = s;
  __syncthreads();
  if (tid == 0) {
    const double t = r2[0] + r2[1] + r2[2] + r2[3];
    out[LOSS_OFF] = (float)(0.25 * t / (double)OUT_Q);
  }
}

extern "C" void kernel_launch(void* const* d_in, const int* in_sizes, int n_in,
                              void* d_out, int out_size, void* d_ws, size_t ws_size,
                              hipStream_t stream) {
  (void)in_sizes; (void)n_in; (void)out_size; (void)ws_size;
  const float* in  = (const float*)d_in[0];
  const float* emb = (const float*)d_in[1];
  float* out = (float*)d_out;
  double* partial = (double*)d_ws;   // 512 doubles, fully overwritten each call
  vq_main<<<NBLK, TPB, 0, stream>>>(in, emb, out, partial);
  vq_loss<<<1, 256, 0, stream>>>(partial, out);
}